// Round 5
// baseline (166.762 us; speedup 1.0000x reference)
//
#include <hip/hip_runtime.h>
#include <stdint.h>

#define K_DIM 1024
#define N_DIM 1024
#define BM 256
#define BN 256
#define BK 64
#define NK (K_DIM / BK)  // 16

typedef __attribute__((ext_vector_type(4))) float f32x4;
typedef __attribute__((ext_vector_type(8))) short bf16x8;
typedef __attribute__((ext_vector_type(4))) uint32_t u32x4;

// round-half-up to bf16, pack two: low 16 = a, high 16 = b
__device__ __forceinline__ uint32_t pack_bf16(float a, float b) {
  uint32_t ua = __builtin_bit_cast(uint32_t, a) + 0x8000u;
  uint32_t ub = __builtin_bit_cast(uint32_t, b) + 0x8000u;
  return __builtin_amdgcn_perm(ub, ua, 0x07060302u);
}

__device__ __forceinline__ float wbin1(float v, float kkv, float aav) {
  float t = v * kkv;
  t = fminf(fmaxf(t, -1.0f), 1.0f);
  return t * aav;
}

// ---------------- kernel 1: w_bin = bf16(aa*clamp(kk*w,-1,1)) into ws ------
__global__ __launch_bounds__(256) void wconv(const float* __restrict__ w,
                                             const float* __restrict__ kkp,
                                             const float* __restrict__ aap,
                                             uint32_t* __restrict__ wb) {
  const float kkv = kkp[0];
  const float aav = aap[0];
  const int g = blockIdx.x * 256 + threadIdx.x;  // 16 floats per thread
  const f32x4* src = (const f32x4*)(w + (size_t)g * 16);
  f32x4 v0 = src[0], v1 = src[1], v2 = src[2], v3 = src[3];
  uint32_t p[8];
#pragma unroll
  for (int i = 0; i < 4; ++i) {
    f32x4 v = i == 0 ? v0 : (i == 1 ? v1 : (i == 2 ? v2 : v3));
    p[2 * i] = pack_bf16(wbin1(v[0], kkv, aav), wbin1(v[1], kkv, aav));
    p[2 * i + 1] = pack_bf16(wbin1(v[2], kkv, aav), wbin1(v[3], kkv, aav));
  }
  u32x4* dst = (u32x4*)(wb + (size_t)g * 8);
  dst[0] = u32x4{p[0], p[1], p[2], p[3]};
  dst[1] = u32x4{p[4], p[5], p[6], p[7]};
}

// ---------------- kernel 2: GEMM -------------------------------------------
// 256x256 tile, 512 threads = 8 waves (2x4), BK=64; wave: 128x64 out.
// LDS dbuf: per buf A[256][64]bf16 (32KB) + B[256][64]bf16 (32KB) = 128 KB.
// Row = 32 u32 = 8 slots x 16B; phys_slot = slot ^ (row&7), both sides.
// T4 counted-vmcnt pipeline, ONE raw s_barrier per tile, vmcnt never 0 in
// steady state: issue A(t+1)[8] + B-DMA(t+1)[4] -> vmcnt(12) retires B(t)
// only -> barrier -> COMPUTE(t) -> WRITEA(t+1) (auto vmcnt(4), covered by
// 64 MFMAs) -> lgkmcnt(0). Per-wave vmem bookkeeping: 8 A-loads + 4 B-DMA
// per tile, in-order retirement makes counted waits exact.
__global__ __launch_bounds__(512, 2) void binlin_gemm(
    const float* __restrict__ x, const uint32_t* __restrict__ wb,
    const float* __restrict__ bias, float* __restrict__ out) {
  __shared__ uint32_t lds[2][(BM + BN) * 32];  // 128 KB

  const int tid = threadIdx.x;

  // bijective XCD swizzle (grid=512): 4 n-blocks of an m-panel -> same L2
  const int per = gridDim.x >> 3;
  const int logical = (blockIdx.x & 7) * per + (blockIdx.x >> 3);
  const int mIdx = logical >> 2;  // N_DIM/BN = 4
  const int nIdx = logical & 3;
  const int row0 = mIdx * BM;
  const int col0 = nIdx * BN;

  // ---- A staging: thread t -> row r = t>>1 (0..255), half h = t&1 ----
  const int r = tid >> 1;
  const int h = tid & 1;
  const int sw = r & 7;
  const float* ga = x + (size_t)(row0 + r) * K_DIM + h * 32;
  const int aoff = r * 32;

  // ---- B staging via global_load_lds: wave w8 -> rows [w8*32, w8*32+32) --
  const int w8 = tid >> 6;
  const int lane = tid & 63;
  const int brow = lane >> 3;
  const int bslot = (lane & 7) ^ brow;  // pre-swizzled source slot
  const uint32_t* gb_base =
      wb + (size_t)(col0 + w8 * 32 + brow) * (K_DIM / 2) + bslot * 4;
  const int boff = (w8 * 32) * 32;

  // ---- compute indices ----
  const int wr = w8 >> 2;
  const int wc = w8 & 3;
  const int cl = lane & 15;
  const int kg = lane >> 4;

  f32x4 acc[8][4] = {};
  f32x4 ra[8];

#define LOADA(kt)                                               \
  {                                                             \
    const f32x4* pa = (const f32x4*)(ga + (kt)*BK);             \
    _Pragma("unroll") for (int i = 0; i < 8; ++i) ra[i] = pa[i];\
  }

#define WRITEA(buf)                                                       \
  {                                                                       \
    uint32_t* lap = &lds[buf][0] + aoff;                                  \
    _Pragma("unroll") for (int j = 0; j < 4; ++j) {                       \
      u32x4 pk = {pack_bf16(ra[2 * j][0], ra[2 * j][1]),                  \
                  pack_bf16(ra[2 * j][2], ra[2 * j][3]),                  \
                  pack_bf16(ra[2 * j + 1][0], ra[2 * j + 1][1]),          \
                  pack_bf16(ra[2 * j + 1][2], ra[2 * j + 1][3])};         \
      *(u32x4*)(lap + (((h * 4 + j) ^ sw) * 4)) = pk;                     \
    }                                                                     \
  }

#define STAGEB(kt, buf)                                                   \
  {                                                                       \
    uint32_t* lbp = &lds[buf][BM * 32] + boff;                            \
    _Pragma("unroll") for (int c = 0; c < 4; ++c) {                       \
      __builtin_amdgcn_global_load_lds(                                   \
          (const __attribute__((address_space(1))) uint32_t*)(            \
              gb_base + (size_t)(c * 8) * (K_DIM / 2) + (kt) * 32),       \
          (__attribute__((address_space(3))) uint32_t*)(lbp + c * 8 * 32),\
          16, 0, 0);                                                      \
    }                                                                     \
  }

#define COMPUTE(buf)                                                           \
  {                                                                            \
    const uint32_t* A = &lds[buf][0];                                          \
    const uint32_t* B = &lds[buf][BM * 32];                                    \
    _Pragma("unroll") for (int ks = 0; ks < 2; ++ks) {                         \
      bf16x8 bfr[4];                                                           \
      _Pragma("unroll") for (int n = 0; n < 4; ++n) {                          \
        int rr = wc * 64 + n * 16 + cl;                                        \
        bfr[n] = *(const bf16x8*)(B + rr * 32 + (((ks * 4 + kg) ^ (rr & 7)) * 4)); \
      }                                                                        \
      _Pragma("unroll") for (int mh = 0; mh < 2; ++mh) {                       \
        bf16x8 af[4];                                                          \
        _Pragma("unroll") for (int m = 0; m < 4; ++m) {                        \
          int rr = wr * 128 + (mh * 4 + m) * 16 + cl;                          \
          af[m] = *(const bf16x8*)(A + rr * 32 + (((ks * 4 + kg) ^ (rr & 7)) * 4)); \
        }                                                                      \
        __builtin_amdgcn_s_setprio(1);                                         \
        _Pragma("unroll") for (int m = 0; m < 4; ++m)                          \
            _Pragma("unroll") for (int n = 0; n < 4; ++n)                      \
                acc[mh * 4 + m][n] = __builtin_amdgcn_mfma_f32_16x16x32_bf16(  \
                    af[m], bfr[n], acc[mh * 4 + m][n], 0, 0, 0);               \
        __builtin_amdgcn_s_setprio(0);                                         \
      }                                                                        \
    }                                                                          \
  }

#define WAIT_VM12() asm volatile("s_waitcnt vmcnt(12)" ::: "memory")
#define WAIT_VM0() asm volatile("s_waitcnt vmcnt(0)" ::: "memory")
#define WAIT_LGKM0() asm volatile("s_waitcnt lgkmcnt(0)" ::: "memory")
#define BAR() __builtin_amdgcn_s_barrier()

  // prologue: stage tile 0 into buf 0, full drain once
  LOADA(0);
  STAGEB(0, 0);
  WRITEA(0);  // compiler-inserted counted vmcnt for ra
  asm volatile("s_waitcnt vmcnt(0) lgkmcnt(0)" ::: "memory");
  BAR();

  for (int kt2 = 0; kt2 < NK; kt2 += 2) {
    // ---- tile kt2 (buf 0) ----
    LOADA(kt2 + 1);
    STAGEB(kt2 + 1, 1);
    WAIT_VM12();  // retire B(kt2); keep A(kt2+1)+B(kt2+1) in flight
    BAR();
    __builtin_amdgcn_sched_barrier(0);
    COMPUTE(0);
    WRITEA(1);     // auto vmcnt(4): A(kt2+1) covered by the 64 MFMAs above
    WAIT_LGKM0();  // ds_writes visible before next barrier
    // ---- tile kt2+1 (buf 1) ----
    if (kt2 + 2 < NK) {
      LOADA(kt2 + 2);
      STAGEB(kt2 + 2, 0);
      WAIT_VM12();  // retire B(kt2+1)
    } else {
      WAIT_VM0();   // last tile: drain B(kt2+1)
    }
    BAR();
    __builtin_amdgcn_sched_barrier(0);
    COMPUTE(1);
    if (kt2 + 2 < NK) {
      WRITEA(0);
      WAIT_LGKM0();
    }
  }

  // epilogue: bias + fp32 store
#pragma unroll
  for (int n = 0; n < 4; ++n) {
    int col = col0 + wc * 64 + n * 16 + cl;
    float bv = bias[col];
#pragma unroll
    for (int m = 0; m < 8; ++m) {
      int rowb = row0 + wr * 128 + m * 16 + kg * 4;
#pragma unroll
      for (int i = 0; i < 4; ++i) {
        out[(size_t)(rowb + i) * N_DIM + col] = acc[m][n][i] + bv;
      }
    }
  }
#undef LOADA
#undef WRITEA
#undef STAGEB
#undef COMPUTE
#undef WAIT_VM12
#undef WAIT_VM0
#undef WAIT_LGKM0
#undef BAR
}

extern "C" void kernel_launch(void* const* d_in, const int* in_sizes, int n_in,
                              void* d_out, int out_size, void* d_ws, size_t ws_size,
                              hipStream_t stream) {
  const float* x = (const float*)d_in[0];
  const float* w = (const float*)d_in[1];
  const float* bias = (const float*)d_in[2];
  const float* kk = (const float*)d_in[3];
  const float* aa = (const float*)d_in[4];
  float* out = (float*)d_out;
  uint32_t* wb = (uint32_t*)d_ws;  // 2 MB bf16 w_bin

  wconv<<<(N_DIM * K_DIM) / (256 * 16), 256, 0, stream>>>(w, kk, aa, wb);

  const int M = in_sizes[0] / K_DIM;         // 32768
  const int grid = (M / BM) * (N_DIM / BN);  // 128 * 4 = 512
  binlin_gemm<<<grid, 512, 0, stream>>>(x, wb, bias, out);
}

// Round 6
// 125.306 us; speedup vs baseline: 1.3308x; 1.3308x over previous
//
#include <hip/hip_runtime.h>
#include <stdint.h>

#define K_DIM 1024
#define N_DIM 1024
#define BM 256
#define BN 256
#define BK 64
#define NK (K_DIM / BK)  // 16

typedef __attribute__((ext_vector_type(4))) float f32x4;
typedef __attribute__((ext_vector_type(8))) short bf16x8;
typedef __attribute__((ext_vector_type(4))) uint32_t u32x4;

// round-half-up to bf16, pack two: low 16 = a, high 16 = b
__device__ __forceinline__ uint32_t pack_bf16(float a, float b) {
  uint32_t ua = __builtin_bit_cast(uint32_t, a) + 0x8000u;
  uint32_t ub = __builtin_bit_cast(uint32_t, b) + 0x8000u;
  return __builtin_amdgcn_perm(ub, ua, 0x07060302u);
}

__device__ __forceinline__ float wbin1(float v, float kkv, float aav) {
  float t = v * kkv;
  t = fminf(fmaxf(t, -1.0f), 1.0f);
  return t * aav;
}

// ---------------- kernel 1: w_bin = bf16(aa*clamp(kk*w,-1,1)) into ws ------
__global__ __launch_bounds__(256) void wconv(const float* __restrict__ w,
                                             const float* __restrict__ kkp,
                                             const float* __restrict__ aap,
                                             uint32_t* __restrict__ wb) {
  const float kkv = kkp[0];
  const float aav = aap[0];
  const int g = blockIdx.x * 256 + threadIdx.x;  // 16 floats per thread
  const f32x4* src = (const f32x4*)(w + (size_t)g * 16);
  f32x4 v0 = src[0], v1 = src[1], v2 = src[2], v3 = src[3];
  uint32_t p[8];
#pragma unroll
  for (int i = 0; i < 4; ++i) {
    f32x4 v = i == 0 ? v0 : (i == 1 ? v1 : (i == 2 ? v2 : v3));
    p[2 * i] = pack_bf16(wbin1(v[0], kkv, aav), wbin1(v[1], kkv, aav));
    p[2 * i + 1] = pack_bf16(wbin1(v[2], kkv, aav), wbin1(v[3], kkv, aav));
  }
  u32x4* dst = (u32x4*)(wb + (size_t)g * 8);
  dst[0] = u32x4{p[0], p[1], p[2], p[3]};
  dst[1] = u32x4{p[4], p[5], p[6], p[7]};
}

// ---------------- kernel 2: x fp32 -> bf16 (packed) into ws ----------------
__global__ __launch_bounds__(256) void xconv(const float* __restrict__ x,
                                             uint32_t* __restrict__ xb) {
  const size_t g = (size_t)blockIdx.x * 256 + threadIdx.x;  // 16 floats
  const f32x4* src = (const f32x4*)(x + g * 16);
  f32x4 v0 = src[0], v1 = src[1], v2 = src[2], v3 = src[3];
  uint32_t p[8];
  p[0] = pack_bf16(v0[0], v0[1]); p[1] = pack_bf16(v0[2], v0[3]);
  p[2] = pack_bf16(v1[0], v1[1]); p[3] = pack_bf16(v1[2], v1[3]);
  p[4] = pack_bf16(v2[0], v2[1]); p[5] = pack_bf16(v2[2], v2[3]);
  p[6] = pack_bf16(v3[0], v3[1]); p[7] = pack_bf16(v3[2], v3[3]);
  u32x4* dst = (u32x4*)(xb + g * 8);
  dst[0] = u32x4{p[0], p[1], p[2], p[3]};
  dst[1] = u32x4{p[4], p[5], p[6], p[7]};
}

// ---------------- kernel 3 (fast): 8-phase 256x256 GEMM --------------------
// m201 template: 256x256 tile, 512 thr = 8 waves (2x4), wave 128x64 out,
// BK=64, LDS dbuf 128 KB. Both operands staged via global_load_lds with
// source-pre-swizzled addresses (slot ^= row&7); reads apply same XOR.
// Per K-tile, 4 phases over C-quadrants (0,0)(0,1)(1,1)(1,0):
//   {ds_reads; [stage 4 DMA]; barrier; lgkmcnt(0); setprio1; 16 MFMA;
//    setprio0; [ph3: vmcnt(0)]; barrier}
// vmcnt(0) only at tile boundary; DMAs for t+1 issued ph0/ph1 of t (3-4
// phases of cover, xb/wb L2/L3-resident).
__global__ __launch_bounds__(512, 2) void binlin_gemm8(
    const uint32_t* __restrict__ xb, const uint32_t* __restrict__ wb,
    const float* __restrict__ bias, float* __restrict__ out) {
  __shared__ uint32_t lds[2][(BM + BN) * 32];  // 128 KB

  const int tid = threadIdx.x;

  // bijective XCD swizzle (grid=512): 4 n-blocks of an m-panel -> same L2
  const int per = gridDim.x >> 3;
  const int logical = (blockIdx.x & 7) * per + (blockIdx.x >> 3);
  const int mIdx = logical >> 2;  // N_DIM/BN = 4
  const int nIdx = logical & 3;
  const int row0 = mIdx * BM;
  const int col0 = nIdx * BN;

  const int w8 = tid >> 6;
  const int lane = tid & 63;
  const int brow = lane >> 3;
  const int bslot = (lane & 7) ^ brow;  // pre-swizzled source slot
  const uint32_t* ga_base =
      xb + (size_t)(row0 + w8 * 32 + brow) * (K_DIM / 2) + bslot * 4;
  const uint32_t* gb_base =
      wb + (size_t)(col0 + w8 * 32 + brow) * (K_DIM / 2) + bslot * 4;

  const int wr = w8 >> 2;
  const int wc = w8 & 3;
  const int cl = lane & 15;
  const int kg = lane >> 4;

  f32x4 acc[8][4] = {};
  bf16x8 af[2][4], bfr[2][2];

#define STAGE_A8(kt, dstbase)                                             \
  do {                                                                    \
    _Pragma("unroll") for (int c4 = 0; c4 < 4; ++c4) {                    \
      __builtin_amdgcn_global_load_lds(                                   \
          (const __attribute__((address_space(1))) uint32_t*)(            \
              ga_base + (size_t)(c4 * 8) * (K_DIM / 2) + (kt) * 32),      \
          (__attribute__((address_space(3))) uint32_t*)(                  \
              (dstbase) + (w8 * 32 + c4 * 8) * 32),                       \
          16, 0, 0);                                                      \
    }                                                                     \
  } while (0)

#define STAGE_B8(kt, dstbase)                                             \
  do {                                                                    \
    _Pragma("unroll") for (int c4 = 0; c4 < 4; ++c4) {                    \
      __builtin_amdgcn_global_load_lds(                                   \
          (const __attribute__((address_space(1))) uint32_t*)(            \
              gb_base + (size_t)(c4 * 8) * (K_DIM / 2) + (kt) * 32),      \
          (__attribute__((address_space(3))) uint32_t*)(                  \
              (dstbase) + BM * 32 + (w8 * 32 + c4 * 8) * 32),             \
          16, 0, 0);                                                      \
    }                                                                     \
  } while (0)

#define READ_AF(AB, MH)                                                        \
  _Pragma("unroll") for (int ks = 0; ks < 2; ++ks)                             \
  _Pragma("unroll") for (int m = 0; m < 4; ++m) {                              \
    int rr = wr * 128 + ((MH)*4 + m) * 16 + cl;                                \
    af[ks][m] =                                                                \
        *(const bf16x8*)((AB) + rr * 32 + (((ks * 4 + kg) ^ (rr & 7)) * 4));   \
  }

#define READ_BF(BB, NH)                                                        \
  _Pragma("unroll") for (int ks = 0; ks < 2; ++ks)                             \
  _Pragma("unroll") for (int n = 0; n < 2; ++n) {                              \
    int rr = wc * 64 + ((NH)*2 + n) * 16 + cl;                                 \
    bfr[ks][n] =                                                               \
        *(const bf16x8*)((BB) + rr * 32 + (((ks * 4 + kg) ^ (rr & 7)) * 4));   \
  }

#define PHTAIL(MH, NH)                                                         \
  __builtin_amdgcn_s_barrier();                                                \
  asm volatile("s_waitcnt lgkmcnt(0)" ::: "memory");                           \
  __builtin_amdgcn_sched_barrier(0);                                           \
  __builtin_amdgcn_s_setprio(1);                                               \
  _Pragma("unroll") for (int ks = 0; ks < 2; ++ks)                             \
  _Pragma("unroll") for (int m = 0; m < 4; ++m)                                \
  _Pragma("unroll") for (int n = 0; n < 2; ++n)                                \
  acc[(MH)*4 + m][(NH)*2 + n] = __builtin_amdgcn_mfma_f32_16x16x32_bf16(       \
      af[ks][m], bfr[ks][n], acc[(MH)*4 + m][(NH)*2 + n], 0, 0, 0);            \
  __builtin_amdgcn_s_setprio(0);

  // prologue: stage tile 0, drain, barrier
  STAGE_A8(0, &lds[0][0]);
  STAGE_B8(0, &lds[0][0]);
  asm volatile("s_waitcnt vmcnt(0)" ::: "memory");
  __builtin_amdgcn_s_barrier();

  for (int kt = 0; kt < NK; ++kt) {
    const uint32_t* AB = &lds[kt & 1][0];
    const uint32_t* BB = AB + BM * 32;
    uint32_t* ND = &lds[(kt & 1) ^ 1][0];
    const bool more = (kt + 1) < NK;
    // ph0: quad (0,0) — stage next A
    READ_AF(AB, 0);
    READ_BF(BB, 0);
    if (more) STAGE_A8(kt + 1, ND);
    PHTAIL(0, 0);
    __builtin_amdgcn_s_barrier();
    // ph1: quad (0,1) — stage next B
    READ_BF(BB, 1);
    if (more) STAGE_B8(kt + 1, ND);
    PHTAIL(0, 1);
    __builtin_amdgcn_s_barrier();
    // ph2: quad (1,1) — reuse bfr
    READ_AF(AB, 1);
    PHTAIL(1, 1);
    __builtin_amdgcn_s_barrier();
    // ph3: quad (1,0) — reuse af; drain staging before boundary barrier
    READ_BF(BB, 0);
    PHTAIL(1, 0);
    asm volatile("s_waitcnt vmcnt(0)" ::: "memory");
    __builtin_amdgcn_s_barrier();
  }

  // epilogue: bias + fp32 store
#pragma unroll
  for (int n = 0; n < 4; ++n) {
    int col = col0 + wc * 64 + n * 16 + cl;
    float bv = bias[col];
#pragma unroll
    for (int m = 0; m < 8; ++m) {
      int rowb = row0 + wr * 128 + m * 16 + kg * 4;
#pragma unroll
      for (int i = 0; i < 4; ++i) {
        out[(size_t)(rowb + i) * N_DIM + col] = acc[m][n][i] + bv;
      }
    }
  }
#undef STAGE_A8
#undef STAGE_B8
#undef READ_AF
#undef READ_BF
#undef PHTAIL
}

// ---------------- fallback GEMM (R5, used when ws too small) ---------------
__global__ __launch_bounds__(512, 2) void binlin_gemm_fb(
    const float* __restrict__ x, const uint32_t* __restrict__ wb,
    const float* __restrict__ bias, float* __restrict__ out) {
  __shared__ uint32_t lds[2][(BM + BN) * 32];

  const int tid = threadIdx.x;
  const int per = gridDim.x >> 3;
  const int logical = (blockIdx.x & 7) * per + (blockIdx.x >> 3);
  const int mIdx = logical >> 2;
  const int nIdx = logical & 3;
  const int row0 = mIdx * BM;
  const int col0 = nIdx * BN;

  const int r = tid >> 1;
  const int h = tid & 1;
  const int sw = r & 7;
  const float* ga = x + (size_t)(row0 + r) * K_DIM + h * 32;
  const int aoff = r * 32;

  const int w8 = tid >> 6;
  const int lane = tid & 63;
  const int brow = lane >> 3;
  const int bslot = (lane & 7) ^ brow;
  const uint32_t* gb_base =
      wb + (size_t)(col0 + w8 * 32 + brow) * (K_DIM / 2) + bslot * 4;
  const int boff = (w8 * 32) * 32;

  const int wr = w8 >> 2;
  const int wc = w8 & 3;
  const int cl = lane & 15;
  const int kg = lane >> 4;

  f32x4 acc[8][4] = {};
  f32x4 ra[8];

#define LOADA(kt)                                                \
  {                                                              \
    const f32x4* pa = (const f32x4*)(ga + (kt)*BK);              \
    _Pragma("unroll") for (int i = 0; i < 8; ++i) ra[i] = pa[i]; \
  }
#define WRITEA(buf)                                                       \
  {                                                                       \
    uint32_t* lap = &lds[buf][0] + aoff;                                  \
    _Pragma("unroll") for (int j = 0; j < 4; ++j) {                       \
      u32x4 pk = {pack_bf16(ra[2 * j][0], ra[2 * j][1]),                  \
                  pack_bf16(ra[2 * j][2], ra[2 * j][3]),                  \
                  pack_bf16(ra[2 * j + 1][0], ra[2 * j + 1][1]),          \
                  pack_bf16(ra[2 * j + 1][2], ra[2 * j + 1][3])};         \
      *(u32x4*)(lap + (((h * 4 + j) ^ sw) * 4)) = pk;                     \
    }                                                                     \
  }
#define STAGEB(kt, buf)                                                    \
  {                                                                        \
    uint32_t* lbp = &lds[buf][BM * 32] + boff;                             \
    _Pragma("unroll") for (int c = 0; c < 4; ++c) {                        \
      __builtin_amdgcn_global_load_lds(                                    \
          (const __attribute__((address_space(1))) uint32_t*)(             \
              gb_base + (size_t)(c * 8) * (K_DIM / 2) + (kt)*32),          \
          (__attribute__((address_space(3))) uint32_t*)(lbp + c * 8 * 32), \
          16, 0, 0);                                                       \
    }                                                                      \
  }
#define COMPUTE(buf)                                                           \
  {                                                                            \
    const uint32_t* A = &lds[buf][0];                                          \
    const uint32_t* B = &lds[buf][BM * 32];                                    \
    _Pragma("unroll") for (int ks = 0; ks < 2; ++ks) {                         \
      bf16x8 bfr[4];                                                           \
      _Pragma("unroll") for (int n = 0; n < 4; ++n) {                          \
        int rr = wc * 64 + n * 16 + cl;                                        \
        bfr[n] =                                                               \
            *(const bf16x8*)(B + rr * 32 + (((ks * 4 + kg) ^ (rr & 7)) * 4));  \
      }                                                                        \
      _Pragma("unroll") for (int mh = 0; mh < 2; ++mh) {                       \
        bf16x8 af[4];                                                          \
        _Pragma("unroll") for (int m = 0; m < 4; ++m) {                        \
          int rr = wr * 128 + (mh * 4 + m) * 16 + cl;                          \
          af[m] =                                                              \
              *(const bf16x8*)(A + rr * 32 + (((ks * 4 + kg) ^ (rr & 7)) * 4));\
        }                                                                      \
        __builtin_amdgcn_s_setprio(1);                                         \
        _Pragma("unroll") for (int m = 0; m < 4; ++m)                          \
            _Pragma("unroll") for (int n = 0; n < 4; ++n)                      \
                acc[mh * 4 + m][n] = __builtin_amdgcn_mfma_f32_16x16x32_bf16(  \
                    af[m], bfr[n], acc[mh * 4 + m][n], 0, 0, 0);               \
        __builtin_amdgcn_s_setprio(0);                                         \
      }                                                                        \
    }                                                                          \
  }

  LOADA(0);
  STAGEB(0, 0);
  WRITEA(0);
  asm volatile("s_waitcnt vmcnt(0) lgkmcnt(0)" ::: "memory");
  __builtin_amdgcn_s_barrier();

  for (int kt2 = 0; kt2 < NK; kt2 += 2) {
    LOADA(kt2 + 1);
    STAGEB(kt2 + 1, 1);
    asm volatile("s_waitcnt vmcnt(12)" ::: "memory");
    __builtin_amdgcn_s_barrier();
    __builtin_amdgcn_sched_barrier(0);
    COMPUTE(0);
    WRITEA(1);
    asm volatile("s_waitcnt lgkmcnt(0)" ::: "memory");
    if (kt2 + 2 < NK) {
      LOADA(kt2 + 2);
      STAGEB(kt2 + 2, 0);
      asm volatile("s_waitcnt vmcnt(12)" ::: "memory");
    } else {
      asm volatile("s_waitcnt vmcnt(0)" ::: "memory");
    }
    __builtin_amdgcn_s_barrier();
    __builtin_amdgcn_sched_barrier(0);
    COMPUTE(1);
    if (kt2 + 2 < NK) {
      WRITEA(0);
      asm volatile("s_waitcnt lgkmcnt(0)" ::: "memory");
    }
  }

#pragma unroll
  for (int n = 0; n < 4; ++n) {
    int col = col0 + wc * 64 + n * 16 + cl;
    float bv = bias[col];
#pragma unroll
    for (int m = 0; m < 8; ++m) {
      int rowb = row0 + wr * 128 + m * 16 + kg * 4;
#pragma unroll
      for (int i = 0; i < 4; ++i) {
        out[(size_t)(rowb + i) * N_DIM + col] = acc[m][n][i] + bv;
      }
    }
  }
#undef LOADA
#undef WRITEA
#undef STAGEB
#undef COMPUTE
}

extern "C" void kernel_launch(void* const* d_in, const int* in_sizes, int n_in,
                              void* d_out, int out_size, void* d_ws, size_t ws_size,
                              hipStream_t stream) {
  const float* x = (const float*)d_in[0];
  const float* w = (const float*)d_in[1];
  const float* bias = (const float*)d_in[2];
  const float* kk = (const float*)d_in[3];
  const float* aa = (const float*)d_in[4];
  float* out = (float*)d_out;

  uint32_t* wb = (uint32_t*)d_ws;  // 2 MB bf16 w_bin at offset 0
  wconv<<<(N_DIM * K_DIM) / (256 * 16), 256, 0, stream>>>(w, kk, aa, wb);

  const int M = in_sizes[0] / K_DIM;         // 32768
  const int grid = (M / BM) * (N_DIM / BN);  // 512

  const size_t wb_bytes = (size_t)N_DIM * K_DIM * 2;            // 2 MB
  const size_t xb_bytes = (size_t)M * K_DIM * 2;                // 64 MB
  if (ws_size >= wb_bytes + xb_bytes) {
    uint32_t* xbp = (uint32_t*)((char*)d_ws + wb_bytes);
    xconv<<<(int)(((size_t)M * K_DIM) / (256 * 16)), 256, 0, stream>>>(x, xbp);
    binlin_gemm8<<<grid, 512, 0, stream>>>(xbp, wb, bias, out);
  } else {
    binlin_gemm_fb<<<grid, 512, 0, stream>>>(x, wb, bias, out);
  }
}